// Round 3
// baseline (2838.759 us; speedup 1.0000x reference)
//
#include <hip/hip_runtime.h>
#include <math.h>
#include <stdint.h>

#define BB 32
#define TT 2048
#define FF 128
#define HH 512
#define FCC 128
#define QW 8
#define NTH 640   // 10 waves: 0-7 compute+add, 8 reader, 9 scorer (WG q==0 only)

#define SCALE_F     1073741824.0f          // 2^30 fixed-point scale
#define INV_SCALE_F (1.0f/1073741824.0f)
#define CNT_ONE     (1ull<<48)             // arrival counter increment
#define LOW_MASK    ((1ull<<48)-1ull)
#define BIAS_TOTAL  (1ll<<46)              // keeps low field positive: no carry into bit 48
#define BIAS_SHARE  (1ll<<43)              // BIAS_TOTAL / 8 (one share per WG, first use of each parity)

typedef float f32x2 __attribute__((ext_vector_type(2)));

__global__ void ws_zero(uint64_t* g) {     // counters/tags must start at 0 (0xAA poison aliases)
    g[(size_t)blockIdx.x * blockDim.x + threadIdx.x] = 0ull;
}

__device__ __forceinline__ void wait_lgkm0() {
    asm volatile("s_waitcnt lgkmcnt(0)" ::: "memory");
}

__device__ __forceinline__ float fast_tanh(float z) {
    float ax = fabsf(z);
    float e  = __expf(-2.0f * ax);
    float r  = (1.0f - e) / (1.0f + e);
    return copysignf(r, z);
}

// packed f32 FMA: d.lo += a.lo*b.lo, d.hi += a.hi*b.hi  (full-rate on CDNA4)
__device__ __forceinline__ void pk_fma(f32x2& d, f32x2 a, f32x2 b) {
    asm("v_pk_fma_f32 %0, %1, %2, %0" : "+v"(d) : "v"(a), "v"(b));
}
__device__ __forceinline__ f32x2 lo2(float4 v) { f32x2 r; r.x = v.x; r.y = v.y; return r; }
__device__ __forceinline__ f32x2 hi2(float4 v) { f32x2 r; r.x = v.z; r.y = v.w; return r; }

// IC-gather RNN. grid=256 (1 WG/CU), b=blk>>3, q=blk&7.
// Transposed ownership: WG q owns COLS [q*64,q*64+64) of W_hh (+ cols
// [q*16..+16) of W_ih/x) for ALL 512 rows. Per step i:
//   waves 0-7 (thread row r=w*64+lane): x-part FIRST (no h dep, hides under
//     flag wait), then read h_i chunk from LDS (broadcast), packed-FMA
//     partial A = W_hh[r][own cols]·h + W_ih[r][own xcols]·x_i, fixed-point
//     delta vs same-parity 2 steps ago, ONE fire-and-forget
//     global_atomic_add((cnt=1)<<48 | delta) to slot[(i+1)&1][b][r].
//   wave 8 (prio 1): polls OWN 64 slots (simple same-address atomic-load
//     do-while — the verified construct; pipelined polling miscompiled under
//     divergent exec in R1/R2), decodes, +bias, tanh, writes LDS h
//     (2-parity) + flag.
//   wave 7 extra: publishes chunk-dot of h_i (tagged u64) into 16-deep ring;
//     wave 9 (WG q==0) consumes ring, counts score>0, writes out[b].
// Parity-slot reuse safe: adds for use n+1 of buf P happen only after every
// WG read use n (read->flag->compute->add causality, as R6/R7). Carry-safe
// u64 packing: low field = 2^46 + A_i*2^30, |A|<2^9 -> field in
// [2^46-2^39, 2^46+2^39], never crosses 0 or 2^48.
__global__ __launch_bounds__(NTH, 1)
void rnn_seq(const float* __restrict__ x, const int* __restrict__ lengths,
             const float* __restrict__ W_ih, const float* __restrict__ W_hh,
             const float* __restrict__ b_ih, const float* __restrict__ b_hh,
             const float* __restrict__ W1, const float* __restrict__ b1,
             const float* __restrict__ W2, const float* __restrict__ b2,
             float* __restrict__ out, uint64_t* __restrict__ ws)
{
    const int blk  = blockIdx.x;
    const int b    = blk >> 3;      // batch (spread mapping)
    const int q    = blk & 7;       // col-chunk owned by this WG
    const int tid  = threadIdx.x;
    const int w    = tid >> 6;
    const int lane = tid & 63;
    const int len  = lengths[b];

    uint64_t* gh  = ws;                         // [2][BB][HH] row accumulators
    uint64_t* gsd = ws + 2 * BB * HH;           // [BB][16][8] scorer ring

    __shared__ float hsh[2][64];                // h chunk, 2-parity
    __shared__ float biass[64];
    __shared__ int   flag_s;                    // highest j with h_j in hsh[j&1]

    if (w == 8) {
        biass[lane] = b_ih[q * 64 + lane] + b_hh[q * 64 + lane];
        hsh[0][lane] = 0.0f;                    // h_0 = 0
        if (lane == 0) flag_s = 0;
    }
    __syncthreads();

    if (w < 8) {
        // ================= compute+add role: row r =================
        const int r = w * 64 + lane;
        float4 ww[16];
        { const float4* p = (const float4*)(W_hh + (size_t)r * HH + q * 64);
          #pragma unroll
          for (int k = 0; k < 16; ++k) ww[k] = p[k]; }
        float4 wi[4];
        { const float4* p = (const float4*)(W_ih + r * FF + q * 16);
          #pragma unroll
          for (int k = 0; k < 4; ++k) wi[k] = p[k]; }
        float wvreg = 0.0f;
        if (w == 7) {                           // scorer weight for col q*64+lane
            const int col = q * 64 + lane;
            #pragma unroll 8
            for (int f = 0; f < FCC; ++f) wvreg += W2[f] * W1[f * HH + col];
        }
        long long prevA[2] = {0, 0};
        const float* xb = x + (size_t)b * TT * FF + q * 16;
        float4 xc[4], xn[4];
        { const float4* p = (const float4*)xb;
          #pragma unroll
          for (int k = 0; k < 4; ++k) xc[k] = p[k]; }
        { const float4* p = (const float4*)(xb + FF);
          #pragma unroll
          for (int k = 0; k < 4; ++k) xn[k] = p[k]; }

        uint64_t* ghb = gh + (size_t)b * HH + r;

        for (int i = 0; i < len; ++i) {
            // ---- x-part first: independent of h, hides under the flag wait
            f32x2 acc01 = {0.0f, 0.0f};
            f32x2 acc23 = {0.0f, 0.0f};
            #pragma unroll
            for (int k = 0; k < 4; ++k) {
                pk_fma(acc01, lo2(wi[k]), lo2(xc[k]));
                pk_fma(acc23, hi2(wi[k]), hi2(xc[k]));
            }

            while (__hip_atomic_load(&flag_s, __ATOMIC_RELAXED,
                                     __HIP_MEMORY_SCOPE_WORKGROUP) < i) {}
            const float* hc = hsh[i & 1];
            const float4* hq = (const float4*)hc;
            #pragma unroll
            for (int k = 0; k < 16; ++k) {
                float4 hk = hq[k];
                pk_fma(acc01, lo2(ww[k]), lo2(hk));
                pk_fma(acc23, hi2(ww[k]), hi2(hk));
            }
            float A = (acc01.x + acc01.y) + (acc23.x + acc23.y);

            float hown = 0.0f;
            if (w == 7) hown = hc[lane];        // capture h_i before add (dep-ordered by publish)

            long long f = llrintf(A * SCALE_F);
            const int pn = (i + 1) & 1;
            long long con = (long long)CNT_ONE + (f - prevA[pn])
                          + ((i < 2) ? BIAS_SHARE : 0);
            prevA[pn] = f;
            atomicAdd((unsigned long long*)(ghb + (size_t)pn * BB * HH),
                      (unsigned long long)con);          // fire-and-forget RMW

            if (w == 7 && i > 0) {              // scorer chunk-dot of h_i
                float d = hown * wvreg;
                d += __shfl_xor(d, 1);  d += __shfl_xor(d, 2);
                d += __shfl_xor(d, 4);  d += __shfl_xor(d, 8);
                d += __shfl_xor(d, 16); d += __shfl_xor(d, 32);
                if (lane == 0) {
                    uint64_t pk = ((uint64_t)(uint32_t)i << 32) |
                                  (uint64_t)__float_as_uint(d);
                    __hip_atomic_store(&gsd[((size_t)b * 16 + (i & 15)) * 8 + q],
                                       pk, __ATOMIC_RELAXED, __HIP_MEMORY_SCOPE_AGENT);
                }
            }
            #pragma unroll
            for (int k = 0; k < 4; ++k) xc[k] = xn[k];
            if (i + 2 < len) {
                const float4* p = (const float4*)(xb + (size_t)(i + 2) * FF);
                #pragma unroll
                for (int k = 0; k < 4; ++k) xn[k] = p[k];
            }
        }
        if (w == 7) {                            // final scorer dot: h_len
            while (__hip_atomic_load(&flag_s, __ATOMIC_RELAXED,
                                     __HIP_MEMORY_SCOPE_WORKGROUP) < len) {}
            float d = hsh[len & 1][lane] * wvreg;
            d += __shfl_xor(d, 1);  d += __shfl_xor(d, 2);
            d += __shfl_xor(d, 4);  d += __shfl_xor(d, 8);
            d += __shfl_xor(d, 16); d += __shfl_xor(d, 32);
            if (lane == 0) {
                uint64_t pk = ((uint64_t)(uint32_t)len << 32) |
                              (uint64_t)__float_as_uint(d);
                __hip_atomic_store(&gsd[((size_t)b * 16 + (len & 15)) * 8 + q],
                                   pk, __ATOMIC_RELAXED, __HIP_MEMORY_SCOPE_AGENT);
            }
        }
    } else if (w == 8) {
        // ================= reader role: own 64 slots =================
        __builtin_amdgcn_s_setprio(1);          // win SIMD arbitration vs spinning compute waves
        float hval = 0.0f;
        for (int i = 0; i < len; ++i) {
            const int j  = i + 1;
            const int pn = j & 1;
            const uint64_t target = 8ull * (uint64_t)((j + 1) >> 1); // 8*uses of this parity
            uint64_t* pr = gh + (size_t)pn * BB * HH + (size_t)b * HH + q * 64 + lane;
            uint64_t u;
            do { u = __hip_atomic_load(pr, __ATOMIC_RELAXED,
                                       __HIP_MEMORY_SCOPE_AGENT); }
            while ((u >> 48) != target);
            long long sf = (long long)(u & LOW_MASK) - BIAS_TOTAL;
            float pre = (float)sf * INV_SCALE_F + biass[lane];
            hval = fast_tanh(pre);
            hsh[pn][lane] = hval;
            wait_lgkm0();
            if (lane == 0)
                __hip_atomic_store(&flag_s, j, __ATOMIC_RELAXED,
                                   __HIP_MEMORY_SCOPE_WORKGROUP);
        }
        out[BB + b * HH + q * 64 + lane] = hval;   // h_final chunk
    } else {
        // ================= scorer consumer (WG q==0 only) =================
        if (q != 0) return;
        float cconst = b2[0];
        for (int f = 0; f < FCC; ++f) cconst += W2[f] * b1[f];
        int count = 0;
        for (int j = 1; j <= len; ++j) {
            float d = 0.0f;
            if (lane < 8) {
                uint64_t* pr = gsd + ((size_t)b * 16 + (j & 15)) * 8 + lane;
                uint64_t u;
                do { u = __hip_atomic_load(pr, __ATOMIC_RELAXED,
                                           __HIP_MEMORY_SCOPE_AGENT); }
                while ((int)(u >> 32) != j);
                d = __uint_as_float((uint32_t)u);
            }
            d += __shfl_xor(d, 1); d += __shfl_xor(d, 2); d += __shfl_xor(d, 4);
            if (lane == 0 && d + cconst > 0.0f) ++count;
        }
        if (lane == 0) out[b] = (float)count;
    }
}

extern "C" void kernel_launch(void* const* d_in, const int* in_sizes, int n_in,
                              void* d_out, int out_size, void* d_ws, size_t ws_size,
                              hipStream_t stream) {
    const float* x    = (const float*)d_in[0];
    const int*   lens = (const int*)d_in[1];
    const float* W_ih = (const float*)d_in[2];
    const float* W_hh = (const float*)d_in[3];
    const float* b_ih = (const float*)d_in[4];
    const float* b_hh = (const float*)d_in[5];
    const float* W1   = (const float*)d_in[6];
    const float* b1   = (const float*)d_in[7];
    const float* W2   = (const float*)d_in[8];
    const float* b2   = (const float*)d_in[9];
    float* out = (float*)d_out;
    uint64_t* ws = (uint64_t*)d_ws;   // 2*32*512 + 32*16*8 = 36864 u64 = 288 KB

    ws_zero<<<dim3(144), dim3(256), 0, stream>>>(ws);
    rnn_seq<<<dim3(BB * QW), dim3(NTH), 0, stream>>>(
        x, lens, W_ih, W_hh, b_ih, b_hh, W1, b1, W2, b2, out, ws);
}